// Round 9
// baseline (389.242 us; speedup 1.0000x reference)
//
#include <hip/hip_runtime.h>
#include <hip/hip_bf16.h>
#include <math.h>

// MoEHeadAdapter: N=65536, D=256, E=4, H=512, K=2, EMB=512.
// Dense-expert compute (all 4 experts scaled by sparse gates) == reference einsum.
// Dtype-agnostic: deterministic per-thread sniff of x encoding (fp32 vs bf16).
//
// R9: scheduler release. R8's SBAR wrapped every s_barrier in sched_barrier(0)
//     PAIRS (288 full scheduling fences/block) -> compiler couldn't hoist/CSE
//     address math across stages (VALUBusy 36.5%, only ~9pts of it gelu).
//     Now: asm("s_barrier":::"memory") - memory ordering kept (clobber = fence;
//     GLDS/barrier are side-effecting vs volatile asm -> no reorder), VALU free.
//     Gelu: exp2f with folded log2e constant (v_exp IS 2^x; saves 1 VALU/gelu).
//     Headline-vs-k_moe gap ~115-125us is fixed harness overhead (constant
//     across ALL k_prep variants R0-R8) - k_moe 252us is the real target.
// ws: [0, 2.25MB) stage-ordered pre-swizzled weight stream (144 x 16KB tiles).
//
// k_moe LDS (70656 B -> 2 blocks/CU):
//   ring slots: s0 [0,16K) s1 [16K,32K) s2 [32K,48K)
//   prologue:  Xs [64][256] bf16 swz @32768 (32K, dies at pre-loop barrier)
//   main:      Hs [64][128] bf16 swz @49152 (16K) | gate_s [64][4] @65536 (1K)
//              wgs [4][256] f32 @66560 (4K, dead after gating)
//   proj:      Ys [64][256] swz @0 (32K) | Peven @32768 | Podd @49152

typedef __attribute__((ext_vector_type(4))) float f32x4;
typedef __attribute__((ext_vector_type(8))) short bf16x8;
typedef unsigned int u32;

#define MFMA16(a, b, c) __builtin_amdgcn_mfma_f32_16x16x32_bf16((a), (b), (c), 0, 0, 0)

#define WAITVM4() asm volatile("s_waitcnt vmcnt(4)" ::: "memory")
#define WAITVM0() asm volatile("s_waitcnt vmcnt(0)" ::: "memory")
#define WAITLG0() asm volatile("s_waitcnt lgkmcnt(0)" ::: "memory")
// Raw barrier with memory-ordering only (no sched_barrier freeze): proven m201
// pattern. "memory" clobber stops loads/stores crossing; VALU may hoist.
#define SBAR() asm volatile("s_barrier" ::: "memory")
#define GLDS16(g, l) __builtin_amdgcn_global_load_lds( \
    (const __attribute__((address_space(1))) u32*)(g), \
    (__attribute__((address_space(3))) u32*)(l), 16, 0, 0)

__device__ __forceinline__ float bf2f(__hip_bfloat16 v) { return __bfloat162float(v); }

__device__ __forceinline__ unsigned short f2bfu(float f) {
    union { __hip_bfloat16 b; unsigned short u; } c;
    c.b = __float2bfloat16(f);
    return c.u;
}

__device__ __forceinline__ float bfu2f(unsigned short u) {
    union { unsigned u; float f; } c;
    c.u = ((unsigned)u) << 16;
    return c.f;
}

// Deterministic dtype sniff: every thread reads the SAME 32 even-position ushorts.
__device__ __forceinline__ bool sniff_f32(const unsigned short* __restrict__ xr) {
    int cnt = 0;
#pragma unroll
    for (int j = 0; j < 32; ++j) {
        int e = (xr[2 * j] >> 7) & 0xFF;
        cnt += (e >= 97 && e <= 157) ? 1 : 0;
    }
    return cnt < 16;
}

// ---------------- K0: stage-ordered, pre-swizzled weight stream (LDS transpose) ----------------
// Identical layout to R4-R8 stream (see R8 header comment for formulas).
__global__ __launch_bounds__(256) void k_prep(
        const void* __restrict__ w1,   // [4][256][512]
        const void* __restrict__ w2,   // [4][512][256]
        const void* __restrict__ wp,   // [256][512]
        const unsigned short* __restrict__ xr,
        char* __restrict__ stream) {
    __shared__ float T[8256];          // A: [64][129] (8256); B/P: [32][257] (8224)
    const int s = blockIdx.x;
    const int t = threadIdx.x;
    const bool f32m = sniff_f32(xr);
    char* dtile = stream + ((size_t)s << 14);

    if (s < 128 && ((s & 31) & 7) < 4) {
        // ---- A-tile: load w1[e][stl*64 .. +64)[hci*128 .. +128) -> T[kq][129] ----
        int e = s >> 5, r = s & 31, hci = r >> 3, stl = r & 7;
        int row = t >> 2;              // kq in [0,64)
        int c0 = (t & 3) * 32;         // h-local start
        size_t soff = ((size_t)e << 17) + (size_t)(stl * 64 + row) * 512 + hci * 128 + c0;
        float* d = &T[row * 129 + c0];
        if (f32m) {
            const float* src = (const float*)w1 + soff;
#pragma unroll
            for (int j = 0; j < 8; ++j) {
                float4 v = *(const float4*)(src + 4 * j);
                d[4 * j + 0] = v.x; d[4 * j + 1] = v.y;
                d[4 * j + 2] = v.z; d[4 * j + 3] = v.w;
            }
        } else {
            const unsigned short* src = (const unsigned short*)w1 + soff;
#pragma unroll
            for (int j = 0; j < 4; ++j) {
                bf16x8 v = *(const bf16x8*)(src + 8 * j);
#pragma unroll
                for (int k = 0; k < 8; ++k)
                    d[8 * j + k] = bfu2f((unsigned short)v[k]);
            }
        }
        __syncthreads();
        // ---- emit 4 consecutive granules/thread (gpos-fast -> coalesced stores) ----
#pragma unroll
        for (int i = 0; i < 4; ++i) {
            int G = t + 256 * i;
            int orow = G >> 3, gpos = G & 7;
            int g = gpos ^ (orow & 7);
            union { unsigned short u[8]; uint4 v; } o;
#pragma unroll
            for (int j = 0; j < 8; ++j)
                o.u[j] = f2bfu(T[(g * 8 + j) * 129 + orow]);
            *(uint4*)(dtile + orow * 128 + gpos * 16) = o.v;
        }
    } else {
        // ---- B-tile / P-tile: load 32 k-rows x 256 cols -> T[kq][257] ----
        size_t soff; int rstride; const void* W;
        if (s < 128) {
            int e = s >> 5, r = s & 31, hci = r >> 3, stl = r & 7;
            int hb0 = hci * 128 + (stl - 4) * 32;
            W = w2; rstride = 256;
            soff = ((size_t)e << 17) + (size_t)hb0 * 256;
        } else {
            int ps = s - 128;
            W = wp; rstride = 512;
            soff = (size_t)((ps & 7) * 32) * 512 + (ps >> 3) * 256;
        }
        int row = t >> 3;              // kq in [0,32)
        int c0 = (t & 7) * 32;         // col-local start
        soff += (size_t)row * rstride + c0;
        float* d = &T[row * 257 + c0];
        if (f32m) {
            const float* src = (const float*)W + soff;
#pragma unroll
            for (int j = 0; j < 8; ++j) {
                float4 v = *(const float4*)(src + 4 * j);
                d[4 * j + 0] = v.x; d[4 * j + 1] = v.y;
                d[4 * j + 2] = v.z; d[4 * j + 3] = v.w;
            }
        } else {
            const unsigned short* src = (const unsigned short*)W + soff;
#pragma unroll
            for (int j = 0; j < 4; ++j) {
                bf16x8 v = *(const bf16x8*)(src + 8 * j);
#pragma unroll
                for (int k = 0; k < 8; ++k)
                    d[8 * j + k] = bfu2f((unsigned short)v[k]);
            }
        }
        __syncthreads();
#pragma unroll
        for (int i = 0; i < 4; ++i) {
            int G = t + 256 * i;
            int orow = G >> 2, gpos = G & 3;
            int g = gpos ^ ((orow >> 1) & 3);
            union { unsigned short u[8]; uint4 v; } o;
#pragma unroll
            for (int j = 0; j < 8; ++j)
                o.u[j] = f2bfu(T[(g * 8 + j) * 257 + orow]);
            *(uint4*)(dtile + orow * 64 + gpos * 16) = o.v;
        }
    }
}

// ---------------- fused: gating + dense expert FFN + out projection ----------------
__global__ __launch_bounds__(256, 2) void k_moe(
    const void* __restrict__ xin,     // [65536][256]
    const void* __restrict__ wg,      // [256][4]
    const char* __restrict__ stream,  // 144 x 16KB
    const void* __restrict__ bp,      // [512]
    void* __restrict__ outp) {        // [65536][512]
    extern __shared__ char smem[];
    char* xsb = smem + 32768;                 // Xs [64][256] bf16, stride 512B, swz
    char* hsb = smem + 49152;                 // Hs [64][128] bf16, stride 256B, swz
    float* gate_s = (float*)(smem + 65536);   // [64][4]
    float* wgs = (float*)(smem + 66560);      // [4][256] f32 (own 4KB; dead after gating)
    char* ysb = smem;                         // Ys [64][256] swz (proj phase)
    char* peven = smem + 32768;               // proj ring even
    char* podd  = smem + 49152;               // proj ring odd

    const int tid = threadIdx.x;
    const int m0 = blockIdx.x * 64;
    const char* src_base = stream + tid * 16;
    const int woff = (tid >> 6) << 10;        // wave-uniform LDS chunk base

    const bool f32m = sniff_f32((const unsigned short*)xin);

    // ---- stage X tile as bf16 into swizzled Xs ----
    if (!f32m) {
        const uint4* xg = (const uint4*)((const __hip_bfloat16*)xin + (size_t)m0 * 256);
#pragma unroll
        for (int i = 0; i < 8; ++i) {
            int f = tid + 256 * i;          // granule index over [64][32]
            int r = f >> 5, c = f & 31;
            *(uint4*)(xsb + r * 512 + ((c * 16) ^ ((r & 7) << 4))) = xg[f];
        }
    } else {
        const float4* xg = (const float4*)((const float*)xin + (size_t)m0 * 256);
#pragma unroll
        for (int i = 0; i < 8; ++i) {
            int f = tid + 256 * i;
            int r = f >> 5, c = f & 31;
            float4 a = xg[2 * f], b = xg[2 * f + 1];
            __hip_bfloat16* d = (__hip_bfloat16*)(xsb + r * 512 + ((c * 16) ^ ((r & 7) << 4)));
            d[0] = __float2bfloat16(a.x); d[1] = __float2bfloat16(a.y);
            d[2] = __float2bfloat16(a.z); d[3] = __float2bfloat16(a.w);
            d[4] = __float2bfloat16(b.x); d[5] = __float2bfloat16(b.y);
            d[6] = __float2bfloat16(b.z); d[7] = __float2bfloat16(b.w);
        }
    }
    {  // w_gate transposed to LDS as f32: wgs[e][d]
#pragma unroll
        for (int e = 0; e < 4; ++e)
            wgs[e * 256 + tid] = f32m ? ((const float*)wg)[tid * 4 + e]
                                      : bf2f(((const __hip_bfloat16*)wg)[tid * 4 + e]);
    }

    // ---- NOW issue ring stages 0,1 (after all prologue loads: vmcnt retires in
    //      order, so issuing last keeps them in flight under gating+topk) ----
    {
        const char* s0 = src_base; char* d0 = smem + woff;
        GLDS16(s0, d0); GLDS16(s0 + 4096, d0 + 4096);
        GLDS16(s0 + 8192, d0 + 8192); GLDS16(s0 + 12288, d0 + 12288);
        const char* s1 = src_base + 16384; char* d1 = smem + 16384 + woff;
        GLDS16(s1, d1); GLDS16(s1 + 4096, d1 + 4096);
        GLDS16(s1 + 8192, d1 + 8192); GLDS16(s1 + 12288, d1 + 12288);
    }
    WAITLG0();   // Xs + wgs ds_writes done (lgkm only; GLDS stay in flight)
    SBAR();

    // ---- gating logits at FULL input precision (top-k is discrete!) ----
    {
        int tok = tid >> 2, ge = tid & 3;
        float acc = 0.f;
        if (f32m) {
            const float4* xrow = (const float4*)((const float*)xin + (size_t)(m0 + tok) * 256);
            const float* wrow = &wgs[ge * 256];
#pragma unroll 8
            for (int qd = 0; qd < 64; ++qd) {
                float4 xv = xrow[qd];
                acc += xv.x * wrow[qd * 4] + xv.y * wrow[qd * 4 + 1]
                     + xv.z * wrow[qd * 4 + 2] + xv.w * wrow[qd * 4 + 3];
            }
        } else {
            const float* wrow = &wgs[ge * 256];
#pragma unroll 4
            for (int d8 = 0; d8 < 32; ++d8) {
                bf16x8 xv = *(const bf16x8*)(xsb + tok * 512 + ((d8 * 16) ^ ((tok & 7) << 4)));
#pragma unroll
                for (int j = 0; j < 8; ++j) {
                    union { unsigned u; float f; } c;
                    c.u = ((unsigned)(unsigned short)xv[j]) << 16;
                    acc += c.f * wrow[d8 * 8 + j];
                }
            }
        }
        gate_s[tok * 4 + ge] = acc;
    }
    WAITLG0();
    SBAR();
    if (tid < 64) {   // top-2 + softmax (ties -> lowest index; strict > keeps first)
        float l[4];
#pragma unroll
        for (int e = 0; e < 4; ++e) l[e] = gate_s[tid * 4 + e];
        int i0 = 0; float v0 = l[0];
#pragma unroll
        for (int e = 1; e < 4; ++e)
            if (l[e] > v0) { v0 = l[e]; i0 = e; }
        int i1 = -1; float v1 = -1e30f;
#pragma unroll
        for (int e = 0; e < 4; ++e)
            if (e != i0 && l[e] > v1) { v1 = l[e]; i1 = e; }
        float t = __expf(v1 - v0);
        float g0 = 1.f / (1.f + t);
        float g1 = t * g0;
#pragma unroll
        for (int e = 0; e < 4; ++e) gate_s[tid * 4 + e] = 0.f;
        gate_s[tid * 4 + i0] = g0;
        gate_s[tid * 4 + i1] = g1;
    }
    WAITLG0();
    SBAR();

    const int lane = tid & 63;
    const int wv = tid >> 6;       // 4 waves
    const int wr = wv & 1;         // rows 32*wr..+32
    const int wc = wv >> 1;        // col group 0/1
    const int lm = lane & 15, quad = lane >> 4;
    const int swzB = quad ^ ((lm >> 1) & 3);   // B/P-tile read swizzle

    // ---- hoist X fragments to registers (Xs dies after the barrier below) ----
    bf16x8 ax[2][8];
#pragma unroll
    for (int mt = 0; mt < 2; ++mt)
#pragma unroll
        for (int ks = 0; ks < 8; ++ks) {
            int row = 32 * wr + 16 * mt + lm;
            ax[mt][ks] = *(const bf16x8*)(xsb + row * 512
                            + (((ks * 64 + quad * 16)) ^ ((row & 7) << 4)));
        }
    WAITVM4();   // stage 0's 4 GLDS retired; stage 1 (possibly) still in flight
    WAITLG0();
    SBAR();      // publish stage 0; Xs dead; slot2 writable

    f32x4 Yacc[2][8];
#pragma unroll
    for (int a = 0; a < 2; ++a)
#pragma unroll
        for (int b = 0; b < 8; ++b) Yacc[a][b] = (f32x4){0.f, 0.f, 0.f, 0.f};

    // invariant at top of iter for stage s: s published; s+1 in flight; s+2 not issued
    int sidx = 0, cur = 0;
#pragma unroll 1
    for (int e = 0; e < 4; ++e) {
#pragma unroll 1
        for (int hci = 0; hci < 4; ++hci) {
            f32x4 Hacc[2][4];
#pragma unroll
            for (int a = 0; a < 2; ++a)
#pragma unroll
                for (int b = 0; b < 4; ++b) Hacc[a][b] = (f32x4){0.f, 0.f, 0.f, 0.f};
            // ---- A-stages (max sidx 123 -> always prefetch) ----
#pragma unroll
            for (int stA = 0; stA < 4; ++stA) {
                const char* rb = smem + cur * 16384;
                bf16x8 bfr[2][4];
#pragma unroll
                for (int ks = 0; ks < 2; ++ks)
#pragma unroll
                    for (int nt = 0; nt < 4; ++nt) {
                        int rown = 64 * wc + 16 * nt + lm;
                        bfr[ks][nt] = *(const bf16x8*)(rb + rown * 128
                                        + ((((ks << 2) | quad) ^ (lm & 7)) << 4));
                    }
                {   // issue stage sidx+2 into slot (cur+2)%3 (== slot(sidx-1), freed)
                    int ns = cur + 2; if (ns >= 3) ns -= 3;
                    const char* sp = src_base + ((size_t)(sidx + 2) << 14);
                    char* dp = smem + ns * 16384 + woff;
                    GLDS16(sp, dp); GLDS16(sp + 4096, dp + 4096);
                    GLDS16(sp + 8192, dp + 8192); GLDS16(sp + 12288, dp + 12288);
                }
                __builtin_amdgcn_s_setprio(1);
#pragma unroll
                for (int ks = 0; ks < 2; ++ks)
#pragma unroll
                    for (int nt = 0; nt < 4; ++nt) {
                        Hacc[0][nt] = MFMA16(ax[0][2 * stA + ks], bfr[ks][nt], Hacc[0][nt]);
                        Hacc[1][nt] = MFMA16(ax[1][2 * stA + ks], bfr[ks][nt], Hacc[1][nt]);
                    }
                __builtin_amdgcn_s_setprio(0);
                if (stA == 3) {   // gelu + gate -> Hs (swizzled); drain ds_writes
#pragma unroll
                    for (int mt = 0; mt < 2; ++mt)
#pragma unroll
                        for (int nt = 0; nt < 4; ++nt)
#pragma unroll
                            for (int r = 0; r < 4; ++r) {
                                int row = 32 * wr + 16 * mt + quad * 4 + r;
                                int col = 64 * wc + 16 * nt + lm;
                                float v = Hacc[mt][nt][r];
                                float vv = v * v;
                                float w = fmaf(0.044715f, vv, 1.0f);
                                // tanh-gelu, exp2 form: 2t*log2e = 2.3022082*v*w
                                float ex = exp2f(2.3022082f * v * w);
                                float rr = __builtin_amdgcn_rcpf(ex + 1.0f);
                                float vg = v * gate_s[row * 4 + e];
                                float res = fmaf(-vg, rr, vg);   // vg*(1-r); inf-safe
                                *(__hip_bfloat16*)(hsb + row * 256
                                    + ((col * 2) ^ ((row & 7) << 4))) = __float2bfloat16(res);
                            }
                    WAITLG0();
                }
                WAITVM4();   // drain stage sidx+1 (leaves sidx+2's 4 in flight)
                SBAR();      // publish sidx+1; slot(sidx) freed for next issue
                ++sidx; cur = (cur < 2) ? cur + 1 : 0;
            }
            // ---- B-stages ----
#pragma unroll
            for (int stB = 0; stB < 4; ++stB) {
                const char* rb = smem + cur * 16384;
                int r0 = 32 * wr + lm;
                bf16x8 af0 = *(const bf16x8*)(hsb + r0 * 256
                                + ((stB * 64 + quad * 16) ^ ((r0 & 7) << 4)));
                bf16x8 af1 = *(const bf16x8*)(hsb + (r0 + 16) * 256
                                + ((stB * 64 + quad * 16) ^ ((r0 & 7) << 4)));
                bf16x8 bfr[8];
#pragma unroll
                for (int nt = 0; nt < 8; ++nt) {
                    int rown = 128 * wc + 16 * nt + lm;
                    bfr[nt] = *(const bf16x8*)(rb + rown * 64 + (swzB << 4));
                }
                bool pf = (sidx + 2 <= 127);
                if (pf) {
                    int ns = cur + 2; if (ns >= 3) ns -= 3;
                    const char* sp = src_base + ((size_t)(sidx + 2) << 14);
                    char* dp = smem + ns * 16384 + woff;
                    GLDS16(sp, dp); GLDS16(sp + 4096, dp + 4096);
                    GLDS16(sp + 8192, dp + 8192); GLDS16(sp + 12288, dp + 12288);
                }
                __builtin_amdgcn_s_setprio(1);
#pragma unroll
                for (int nt = 0; nt < 8; ++nt) {
                    Yacc[0][nt] = MFMA16(af0, bfr[nt], Yacc[0][nt]);
                    Yacc[1][nt] = MFMA16(af1, bfr[nt], Yacc[1][nt]);
                }
                __builtin_amdgcn_s_setprio(0);
                if (pf) WAITVM4(); else WAITVM0();
                SBAR();
                ++sidx; cur = (cur < 2) ? cur + 1 : 0;
            }
        }
    }

    // ---- transition: issue P0/P1, stash Y (swizzled) into dead ring slots 0/1 ----
    {
        const char* s0 = stream + ((size_t)128 << 14) + tid * 16;
        char* d0 = peven + woff;
        GLDS16(s0, d0); GLDS16(s0 + 4096, d0 + 4096);
        GLDS16(s0 + 8192, d0 + 8192); GLDS16(s0 + 12288, d0 + 12288);
        const char* s1 = stream + ((size_t)129 << 14) + tid * 16;
        char* d1 = podd + woff;
        GLDS16(s1, d1); GLDS16(s1 + 4096, d1 + 4096);
        GLDS16(s1 + 8192, d1 + 8192); GLDS16(s1 + 12288, d1 + 12288);
    }
#pragma unroll
    for (int mt = 0; mt < 2; ++mt)   // Y -> Ys (hides P0/P1 latency)
#pragma unroll
        for (int nt = 0; nt < 8; ++nt)
#pragma unroll
            for (int r = 0; r < 4; ++r) {
                int row = 32 * wr + 16 * mt + quad * 4 + r;
                int col = 128 * wc + 16 * nt + lm;
                *(__hip_bfloat16*)(ysb + row * 512
                    + ((col * 2) ^ ((row & 7) << 4))) = __float2bfloat16(Yacc[mt][nt][r]);
            }
    WAITLG0();
    WAITVM4();   // P0 landed, P1 in flight
    SBAR();

    // ---- projection: OUT[64][512] = Y @ Wproj + b; 16 stages, 2-slot ring ----
    f32x4 Pacc[2][8];
#pragma unroll
    for (int a = 0; a < 2; ++a)
#pragma unroll
        for (int b = 0; b < 8; ++b) Pacc[a][b] = (f32x4){0.f, 0.f, 0.f, 0.f};
#pragma unroll 1
    for (int ps = 0; ps < 16; ++ps) {
        int t = ps & 7;
        const char* pb = (ps & 1) ? podd : peven;
        int r0 = 32 * wr + lm;
        bf16x8 af0 = *(const bf16x8*)(ysb + r0 * 512
                        + ((t * 64 + quad * 16) ^ ((r0 & 7) << 4)));
        bf16x8 af1 = *(const bf16x8*)(ysb + (r0 + 16) * 512
                        + ((t * 64 + quad * 16) ^ ((r0 & 7) << 4)));
        bf16x8 bfr[8];
#pragma unroll
        for (int nt = 0; nt < 8; ++nt) {
            int rown = 128 * wc + 16 * nt + lm;
            bfr[nt] = *(const bf16x8*)(pb + rown * 64 + (swzB << 4));
        }
        __builtin_amdgcn_s_setprio(1);
#pragma unroll
        for (int nt = 0; nt < 8; ++nt) {
            Pacc[0][nt] = MFMA16(af0, bfr[nt], Pacc[0][nt]);
            Pacc[1][nt] = MFMA16(af1, bfr[nt], Pacc[1][nt]);
        }
        __builtin_amdgcn_s_setprio(0);
        if (ps < 15) {
            WAITVM0();   // drain P(ps+1) (+ any epilogue stores)
            SBAR();      // publish P(ps+1); all waves' reads of slot(ps) retired
            if (ps + 2 <= 15) {
                const char* sp = stream + ((size_t)(130 + ps) << 14) + tid * 16;
                char* dp = ((ps & 1) ? podd : peven) + woff;   // slot(ps+2)==slot(ps)
                GLDS16(sp, dp); GLDS16(sp + 4096, dp + 4096);
                GLDS16(sp + 8192, dp + 8192); GLDS16(sp + 12288, dp + 12288);
            }
        }
        if (t == 7) {   // epilogue for p = ps>>3 (after barrier: stores off the wait path)
            int p = ps >> 3;
#pragma unroll
            for (int nt = 0; nt < 8; ++nt) {
                int col = 256 * p + 128 * wc + 16 * nt + lm;
                float bv = f32m ? ((const float*)bp)[col] : bf2f(((const __hip_bfloat16*)bp)[col]);
#pragma unroll
                for (int mt = 0; mt < 2; ++mt)
#pragma unroll
                    for (int r = 0; r < 4; ++r) {
                        int row = m0 + 32 * wr + 16 * mt + quad * 4 + r;
                        float v = Pacc[mt][nt][r] + bv;
                        if (f32m) ((float*)outp)[(size_t)row * 512 + col] = v;
                        else ((__hip_bfloat16*)outp)[(size_t)row * 512 + col] = __float2bfloat16(v);
                    }
            }
            if (ps < 15) {
#pragma unroll
                for (int a = 0; a < 2; ++a)
#pragma unroll
                    for (int b = 0; b < 8; ++b) Pacc[a][b] = (f32x4){0.f, 0.f, 0.f, 0.f};
            }
        }
    }
}

extern "C" void kernel_launch(void* const* d_in, const int* in_sizes, int n_in,
                              void* d_out, int out_size, void* d_ws, size_t ws_size,
                              hipStream_t stream) {
    const void* x  = d_in[0];
    const void* wg = d_in[1];
    const void* w1 = d_in[2];
    const void* w2 = d_in[3];
    const void* wp = d_in[4];
    const void* bp = d_in[5];

    char* wstream = (char*)d_ws;   // 144 x 16384 = 2359296 B

    k_prep<<<144, 256, 0, stream>>>(w1, w2, wp, (const unsigned short*)x, wstream);
    k_moe<<<1024, 256, 70656, stream>>>(x, wg, wstream, bp, d_out);
}

// Round 10
// 372.157 us; speedup vs baseline: 1.0459x; 1.0459x over previous
//
#include <hip/hip_runtime.h>
#include <hip/hip_bf16.h>
#include <math.h>

// MoEHeadAdapter: N=65536, D=256, E=4, H=512, K=2, EMB=512.
// Dense-expert compute (all 4 experts scaled by sparse gates) == reference einsum.
// Dtype-agnostic: deterministic per-thread sniff of x encoding (fp32 vs bf16).
//
// R10 = R8 (best known: 252.4us k_moe) + two bounded fixes:
//  - R9's raw-barrier regressed (252->266, VALUBusy 36.5->40.7): sched_barrier-framed
//    SBAR is the better codegen anchor on this kernel. Reverted (incl. __expf gelu).
//  - gate-hoist: gelu read gate_s 32x/phase inside nt-loop (nt-independent row;
//    compiler can't CSE LDS loads past hsb ds_writes). Now 8 reads/phase.
//  - proj 3-slot ring @32768/49152/65536 (LDS 70656->81920, still 2 blocks/CU):
//    counted vmcnt(4) + rotation issue replaces 14x vmcnt(0) drains.
// ws: [0, 2.25MB) stage-ordered pre-swizzled weight stream (144 x 16KB tiles).
//
// k_moe LDS (81920 B -> exactly 2 blocks/CU):
//   ring slots: s0 [0,16K) s1 [16K,32K) s2 [32K,48K)
//   prologue:  Xs [64][256] bf16 swz @32768 (32K, dies at pre-loop barrier)
//   main:      Hs [64][128] bf16 swz @49152 (16K) | gate_s [64][4] @65536 (1K)
//              wgs [4][256] f32 @66560 (4K, dead after gating)
//   proj:      Ys [64][256] swz @0 (32K) | P-slots @32768/49152/65536 (Hs/gate/wgs dead)

typedef __attribute__((ext_vector_type(4))) float f32x4;
typedef __attribute__((ext_vector_type(8))) short bf16x8;
typedef unsigned int u32;

#define MFMA16(a, b, c) __builtin_amdgcn_mfma_f32_16x16x32_bf16((a), (b), (c), 0, 0, 0)

#define WAITVM4() asm volatile("s_waitcnt vmcnt(4)" ::: "memory")
#define WAITVM0() asm volatile("s_waitcnt vmcnt(0)" ::: "memory")
#define WAITLG0() asm volatile("s_waitcnt lgkmcnt(0)" ::: "memory")
#define SBAR() do { __builtin_amdgcn_sched_barrier(0); \
                    __builtin_amdgcn_s_barrier(); \
                    __builtin_amdgcn_sched_barrier(0); } while (0)
#define GLDS16(g, l) __builtin_amdgcn_global_load_lds( \
    (const __attribute__((address_space(1))) u32*)(g), \
    (__attribute__((address_space(3))) u32*)(l), 16, 0, 0)

__device__ __forceinline__ float bf2f(__hip_bfloat16 v) { return __bfloat162float(v); }

__device__ __forceinline__ unsigned short f2bfu(float f) {
    union { __hip_bfloat16 b; unsigned short u; } c;
    c.b = __float2bfloat16(f);
    return c.u;
}

__device__ __forceinline__ float bfu2f(unsigned short u) {
    union { unsigned u; float f; } c;
    c.u = ((unsigned)u) << 16;
    return c.f;
}

// Deterministic dtype sniff: every thread reads the SAME 32 even-position ushorts.
__device__ __forceinline__ bool sniff_f32(const unsigned short* __restrict__ xr) {
    int cnt = 0;
#pragma unroll
    for (int j = 0; j < 32; ++j) {
        int e = (xr[2 * j] >> 7) & 0xFF;
        cnt += (e >= 97 && e <= 157) ? 1 : 0;
    }
    return cnt < 16;
}

// ---------------- K0: stage-ordered, pre-swizzled weight stream (LDS transpose) ----------------
// Identical layout to R4-R9 stream (see formulas in comments below).
//  s<128: e=s>>5, r=s&31, hci=r>>3, stl=r&7.
//   A (stl<4):  granule(row,gpos): g=gpos^(row&7); src w1[e][stl*64+g*8+j][hci*128+row]
//   B (stl>=4): g=gpos^((row>>1)&3); src w2[e][hci*128+(stl-4)*32+g*8+j][row]
//  s>=128: ps=s-128: g=gpos^((row>>1)&3); src wp[(ps&7)*32+g*8+j][(ps>>3)*256+row]
__global__ __launch_bounds__(256) void k_prep(
        const void* __restrict__ w1,   // [4][256][512]
        const void* __restrict__ w2,   // [4][512][256]
        const void* __restrict__ wp,   // [256][512]
        const unsigned short* __restrict__ xr,
        char* __restrict__ stream) {
    __shared__ float T[8256];          // A: [64][129] (8256); B/P: [32][257] (8224)
    const int s = blockIdx.x;
    const int t = threadIdx.x;
    const bool f32m = sniff_f32(xr);
    char* dtile = stream + ((size_t)s << 14);

    if (s < 128 && ((s & 31) & 7) < 4) {
        // ---- A-tile: load w1[e][stl*64 .. +64)[hci*128 .. +128) -> T[kq][129] ----
        int e = s >> 5, r = s & 31, hci = r >> 3, stl = r & 7;
        int row = t >> 2;              // kq in [0,64)
        int c0 = (t & 3) * 32;         // h-local start
        size_t soff = ((size_t)e << 17) + (size_t)(stl * 64 + row) * 512 + hci * 128 + c0;
        float* d = &T[row * 129 + c0];
        if (f32m) {
            const float* src = (const float*)w1 + soff;
#pragma unroll
            for (int j = 0; j < 8; ++j) {
                float4 v = *(const float4*)(src + 4 * j);
                d[4 * j + 0] = v.x; d[4 * j + 1] = v.y;
                d[4 * j + 2] = v.z; d[4 * j + 3] = v.w;
            }
        } else {
            const unsigned short* src = (const unsigned short*)w1 + soff;
#pragma unroll
            for (int j = 0; j < 4; ++j) {
                bf16x8 v = *(const bf16x8*)(src + 8 * j);
#pragma unroll
                for (int k = 0; k < 8; ++k)
                    d[8 * j + k] = bfu2f((unsigned short)v[k]);
            }
        }
        __syncthreads();
        // ---- emit 4 consecutive granules/thread (gpos-fast -> coalesced stores) ----
#pragma unroll
        for (int i = 0; i < 4; ++i) {
            int G = t + 256 * i;
            int orow = G >> 3, gpos = G & 7;
            int g = gpos ^ (orow & 7);
            union { unsigned short u[8]; uint4 v; } o;
#pragma unroll
            for (int j = 0; j < 8; ++j)
                o.u[j] = f2bfu(T[(g * 8 + j) * 129 + orow]);
            *(uint4*)(dtile + orow * 128 + gpos * 16) = o.v;
        }
    } else {
        // ---- B-tile / P-tile: load 32 k-rows x 256 cols -> T[kq][257] ----
        size_t soff; int rstride; const void* W;
        if (s < 128) {
            int e = s >> 5, r = s & 31, hci = r >> 3, stl = r & 7;
            int hb0 = hci * 128 + (stl - 4) * 32;
            W = w2; rstride = 256;
            soff = ((size_t)e << 17) + (size_t)hb0 * 256;
        } else {
            int ps = s - 128;
            W = wp; rstride = 512;
            soff = (size_t)((ps & 7) * 32) * 512 + (ps >> 3) * 256;
        }
        int row = t >> 3;              // kq in [0,32)
        int c0 = (t & 7) * 32;         // col-local start
        soff += (size_t)row * rstride + c0;
        float* d = &T[row * 257 + c0];
        if (f32m) {
            const float* src = (const float*)W + soff;
#pragma unroll
            for (int j = 0; j < 8; ++j) {
                float4 v = *(const float4*)(src + 4 * j);
                d[4 * j + 0] = v.x; d[4 * j + 1] = v.y;
                d[4 * j + 2] = v.z; d[4 * j + 3] = v.w;
            }
        } else {
            const unsigned short* src = (const unsigned short*)W + soff;
#pragma unroll
            for (int j = 0; j < 4; ++j) {
                bf16x8 v = *(const bf16x8*)(src + 8 * j);
#pragma unroll
                for (int k = 0; k < 8; ++k)
                    d[8 * j + k] = bfu2f((unsigned short)v[k]);
            }
        }
        __syncthreads();
#pragma unroll
        for (int i = 0; i < 4; ++i) {
            int G = t + 256 * i;
            int orow = G >> 2, gpos = G & 3;
            int g = gpos ^ ((orow >> 1) & 3);
            union { unsigned short u[8]; uint4 v; } o;
#pragma unroll
            for (int j = 0; j < 8; ++j)
                o.u[j] = f2bfu(T[(g * 8 + j) * 257 + orow]);
            *(uint4*)(dtile + orow * 64 + gpos * 16) = o.v;
        }
    }
}

// ---------------- fused: gating + dense expert FFN + out projection ----------------
__global__ __launch_bounds__(256, 2) void k_moe(
    const void* __restrict__ xin,     // [65536][256]
    const void* __restrict__ wg,      // [256][4]
    const char* __restrict__ stream,  // 144 x 16KB
    const void* __restrict__ bp,      // [512]
    void* __restrict__ outp) {        // [65536][512]
    extern __shared__ char smem[];
    char* xsb = smem + 32768;                 // Xs [64][256] bf16, stride 512B, swz
    char* hsb = smem + 49152;                 // Hs [64][128] bf16, stride 256B, swz
    float* gate_s = (float*)(smem + 65536);   // [64][4]
    float* wgs = (float*)(smem + 66560);      // [4][256] f32 (dead after gating)
    char* ysb = smem;                         // Ys [64][256] swz (proj phase)
    char* pring = smem + 32768;               // proj slots: 3 x 16K @32768/49152/65536

    const int tid = threadIdx.x;
    const int m0 = blockIdx.x * 64;
    const char* src_base = stream + tid * 16;
    const int woff = (tid >> 6) << 10;        // wave-uniform LDS chunk base

    const bool f32m = sniff_f32((const unsigned short*)xin);

    // ---- stage X tile as bf16 into swizzled Xs ----
    if (!f32m) {
        const uint4* xg = (const uint4*)((const __hip_bfloat16*)xin + (size_t)m0 * 256);
#pragma unroll
        for (int i = 0; i < 8; ++i) {
            int f = tid + 256 * i;          // granule index over [64][32]
            int r = f >> 5, c = f & 31;
            *(uint4*)(xsb + r * 512 + ((c * 16) ^ ((r & 7) << 4))) = xg[f];
        }
    } else {
        const float4* xg = (const float4*)((const float*)xin + (size_t)m0 * 256);
#pragma unroll
        for (int i = 0; i < 8; ++i) {
            int f = tid + 256 * i;
            int r = f >> 5, c = f & 31;
            float4 a = xg[2 * f], b = xg[2 * f + 1];
            __hip_bfloat16* d = (__hip_bfloat16*)(xsb + r * 512 + ((c * 16) ^ ((r & 7) << 4)));
            d[0] = __float2bfloat16(a.x); d[1] = __float2bfloat16(a.y);
            d[2] = __float2bfloat16(a.z); d[3] = __float2bfloat16(a.w);
            d[4] = __float2bfloat16(b.x); d[5] = __float2bfloat16(b.y);
            d[6] = __float2bfloat16(b.z); d[7] = __float2bfloat16(b.w);
        }
    }
    {  // w_gate transposed to LDS as f32: wgs[e][d]
#pragma unroll
        for (int e = 0; e < 4; ++e)
            wgs[e * 256 + tid] = f32m ? ((const float*)wg)[tid * 4 + e]
                                      : bf2f(((const __hip_bfloat16*)wg)[tid * 4 + e]);
    }

    // ---- NOW issue ring stages 0,1 (after all prologue loads: vmcnt retires in
    //      order, so issuing last keeps them in flight under gating+topk) ----
    {
        const char* s0 = src_base; char* d0 = smem + woff;
        GLDS16(s0, d0); GLDS16(s0 + 4096, d0 + 4096);
        GLDS16(s0 + 8192, d0 + 8192); GLDS16(s0 + 12288, d0 + 12288);
        const char* s1 = src_base + 16384; char* d1 = smem + 16384 + woff;
        GLDS16(s1, d1); GLDS16(s1 + 4096, d1 + 4096);
        GLDS16(s1 + 8192, d1 + 8192); GLDS16(s1 + 12288, d1 + 12288);
    }
    WAITLG0();   // Xs + wgs ds_writes done (lgkm only; GLDS stay in flight)
    SBAR();

    // ---- gating logits at FULL input precision (top-k is discrete!) ----
    {
        int tok = tid >> 2, ge = tid & 3;
        float acc = 0.f;
        if (f32m) {
            const float4* xrow = (const float4*)((const float*)xin + (size_t)(m0 + tok) * 256);
            const float* wrow = &wgs[ge * 256];
#pragma unroll 8
            for (int qd = 0; qd < 64; ++qd) {
                float4 xv = xrow[qd];
                acc += xv.x * wrow[qd * 4] + xv.y * wrow[qd * 4 + 1]
                     + xv.z * wrow[qd * 4 + 2] + xv.w * wrow[qd * 4 + 3];
            }
        } else {
            const float* wrow = &wgs[ge * 256];
#pragma unroll 4
            for (int d8 = 0; d8 < 32; ++d8) {
                bf16x8 xv = *(const bf16x8*)(xsb + tok * 512 + ((d8 * 16) ^ ((tok & 7) << 4)));
#pragma unroll
                for (int j = 0; j < 8; ++j) {
                    union { unsigned u; float f; } c;
                    c.u = ((unsigned)(unsigned short)xv[j]) << 16;
                    acc += c.f * wrow[d8 * 8 + j];
                }
            }
        }
        gate_s[tok * 4 + ge] = acc;
    }
    WAITLG0();
    SBAR();
    if (tid < 64) {   // top-2 + softmax (ties -> lowest index; strict > keeps first)
        float l[4];
#pragma unroll
        for (int e = 0; e < 4; ++e) l[e] = gate_s[tid * 4 + e];
        int i0 = 0; float v0 = l[0];
#pragma unroll
        for (int e = 1; e < 4; ++e)
            if (l[e] > v0) { v0 = l[e]; i0 = e; }
        int i1 = -1; float v1 = -1e30f;
#pragma unroll
        for (int e = 0; e < 4; ++e)
            if (e != i0 && l[e] > v1) { v1 = l[e]; i1 = e; }
        float t = __expf(v1 - v0);
        float g0 = 1.f / (1.f + t);
        float g1 = t * g0;
#pragma unroll
        for (int e = 0; e < 4; ++e) gate_s[tid * 4 + e] = 0.f;
        gate_s[tid * 4 + i0] = g0;
        gate_s[tid * 4 + i1] = g1;
    }
    WAITLG0();
    SBAR();

    const int lane = tid & 63;
    const int wv = tid >> 6;       // 4 waves
    const int wr = wv & 1;         // rows 32*wr..+32
    const int wc = wv >> 1;        // col group 0/1
    const int lm = lane & 15, quad = lane >> 4;
    const int swzB = quad ^ ((lm >> 1) & 3);   // B/P-tile read swizzle

    // ---- hoist X fragments to registers (Xs dies after the barrier below) ----
    bf16x8 ax[2][8];
#pragma unroll
    for (int mt = 0; mt < 2; ++mt)
#pragma unroll
        for (int ks = 0; ks < 8; ++ks) {
            int row = 32 * wr + 16 * mt + lm;
            ax[mt][ks] = *(const bf16x8*)(xsb + row * 512
                            + (((ks * 64 + quad * 16)) ^ ((row & 7) << 4)));
        }
    WAITLG0();   // ax reads complete (defensive: slot2 overlays Xs tail)
    WAITVM4();   // stage 0's 4 GLDS retired; stage 1 (possibly) still in flight
    SBAR();      // publish stage 0; Xs dead; slot2 writable

    f32x4 Yacc[2][8];
#pragma unroll
    for (int a = 0; a < 2; ++a)
#pragma unroll
        for (int b = 0; b < 8; ++b) Yacc[a][b] = (f32x4){0.f, 0.f, 0.f, 0.f};

    // invariant at top of iter for stage s: s published; s+1 in flight; s+2 not issued
    int sidx = 0, cur = 0;
#pragma unroll 1
    for (int e = 0; e < 4; ++e) {
#pragma unroll 1
        for (int hci = 0; hci < 4; ++hci) {
            f32x4 Hacc[2][4];
#pragma unroll
            for (int a = 0; a < 2; ++a)
#pragma unroll
                for (int b = 0; b < 4; ++b) Hacc[a][b] = (f32x4){0.f, 0.f, 0.f, 0.f};
            // ---- A-stages (max sidx 123 -> always prefetch) ----
#pragma unroll
            for (int stA = 0; stA < 4; ++stA) {
                const char* rb = smem + cur * 16384;
                bf16x8 bfr[2][4];
#pragma unroll
                for (int ks = 0; ks < 2; ++ks)
#pragma unroll
                    for (int nt = 0; nt < 4; ++nt) {
                        int rown = 64 * wc + 16 * nt + lm;
                        bfr[ks][nt] = *(const bf16x8*)(rb + rown * 128
                                        + ((((ks << 2) | quad) ^ (lm & 7)) << 4));
                    }
                {   // issue stage sidx+2 into slot (cur+2)%3 (== slot(sidx-1), freed)
                    int ns = cur + 2; if (ns >= 3) ns -= 3;
                    const char* sp = src_base + ((size_t)(sidx + 2) << 14);
                    char* dp = smem + ns * 16384 + woff;
                    GLDS16(sp, dp); GLDS16(sp + 4096, dp + 4096);
                    GLDS16(sp + 8192, dp + 8192); GLDS16(sp + 12288, dp + 12288);
                }
                __builtin_amdgcn_s_setprio(1);
#pragma unroll
                for (int ks = 0; ks < 2; ++ks)
#pragma unroll
                    for (int nt = 0; nt < 4; ++nt) {
                        Hacc[0][nt] = MFMA16(ax[0][2 * stA + ks], bfr[ks][nt], Hacc[0][nt]);
                        Hacc[1][nt] = MFMA16(ax[1][2 * stA + ks], bfr[ks][nt], Hacc[1][nt]);
                    }
                __builtin_amdgcn_s_setprio(0);
                if (stA == 3) {   // gelu + gate -> Hs (swizzled); drain ds_writes
                    // gate hoist: row is nt-independent -> 8 LDS reads, not 32
                    float gv[2][4];
#pragma unroll
                    for (int mt = 0; mt < 2; ++mt)
#pragma unroll
                        for (int r = 0; r < 4; ++r)
                            gv[mt][r] = gate_s[(32 * wr + 16 * mt + quad * 4 + r) * 4 + e];
#pragma unroll
                    for (int mt = 0; mt < 2; ++mt)
#pragma unroll
                        for (int nt = 0; nt < 4; ++nt)
#pragma unroll
                            for (int r = 0; r < 4; ++r) {
                                int row = 32 * wr + 16 * mt + quad * 4 + r;
                                int col = 64 * wc + 16 * nt + lm;
                                float v = Hacc[mt][nt][r];
                                float vv = v * v;
                                float w = fmaf(0.044715f, vv, 1.0f);
                                float u = 1.5957691216f * v * w;
                                float ex = __expf(u);
                                float rr = __builtin_amdgcn_rcpf(ex + 1.0f);
                                float vg = v * gv[mt][r];
                                float res = fmaf(-vg, rr, vg);   // vg*(1-r); inf-safe
                                *(__hip_bfloat16*)(hsb + row * 256
                                    + ((col * 2) ^ ((row & 7) << 4))) = __float2bfloat16(res);
                            }
                    WAITLG0();
                }
                WAITVM4();   // drain stage sidx+1 (leaves sidx+2's 4 in flight)
                SBAR();      // publish sidx+1; slot(sidx) freed for next issue
                ++sidx; cur = (cur < 2) ? cur + 1 : 0;
            }
            // ---- B-stages ----
#pragma unroll
            for (int stB = 0; stB < 4; ++stB) {
                const char* rb = smem + cur * 16384;
                int r0 = 32 * wr + lm;
                bf16x8 af0 = *(const bf16x8*)(hsb + r0 * 256
                                + ((stB * 64 + quad * 16) ^ ((r0 & 7) << 4)));
                bf16x8 af1 = *(const bf16x8*)(hsb + (r0 + 16) * 256
                                + ((stB * 64 + quad * 16) ^ ((r0 & 7) << 4)));
                bf16x8 bfr[8];
#pragma unroll
                for (int nt = 0; nt < 8; ++nt) {
                    int rown = 128 * wc + 16 * nt + lm;
                    bfr[nt] = *(const bf16x8*)(rb + rown * 64 + (swzB << 4));
                }
                bool pf = (sidx + 2 <= 127);
                if (pf) {
                    int ns = cur + 2; if (ns >= 3) ns -= 3;
                    const char* sp = src_base + ((size_t)(sidx + 2) << 14);
                    char* dp = smem + ns * 16384 + woff;
                    GLDS16(sp, dp); GLDS16(sp + 4096, dp + 4096);
                    GLDS16(sp + 8192, dp + 8192); GLDS16(sp + 12288, dp + 12288);
                }
                __builtin_amdgcn_s_setprio(1);
#pragma unroll
                for (int nt = 0; nt < 8; ++nt) {
                    Yacc[0][nt] = MFMA16(af0, bfr[nt], Yacc[0][nt]);
                    Yacc[1][nt] = MFMA16(af1, bfr[nt], Yacc[1][nt]);
                }
                __builtin_amdgcn_s_setprio(0);
                if (pf) WAITVM4(); else WAITVM0();
                SBAR();
                ++sidx; cur = (cur < 2) ? cur + 1 : 0;
            }
        }
    }

    // ---- transition: issue P0/P1 into proj slots 0/1, stash Y (swizzled) ----
    {
        const char* s0 = stream + ((size_t)128 << 14) + tid * 16;
        char* d0 = pring + woff;                      // slot0 @32768
        GLDS16(s0, d0); GLDS16(s0 + 4096, d0 + 4096);
        GLDS16(s0 + 8192, d0 + 8192); GLDS16(s0 + 12288, d0 + 12288);
        const char* s1 = stream + ((size_t)129 << 14) + tid * 16;
        char* d1 = pring + 16384 + woff;              // slot1 @49152
        GLDS16(s1, d1); GLDS16(s1 + 4096, d1 + 4096);
        GLDS16(s1 + 8192, d1 + 8192); GLDS16(s1 + 12288, d1 + 12288);
    }
#pragma unroll
    for (int mt = 0; mt < 2; ++mt)   // Y -> Ys (hides P0/P1 latency)
#pragma unroll
        for (int nt = 0; nt < 8; ++nt)
#pragma unroll
            for (int r = 0; r < 4; ++r) {
                int row = 32 * wr + 16 * mt + quad * 4 + r;
                int col = 128 * wc + 16 * nt + lm;
                *(__hip_bfloat16*)(ysb + row * 512
                    + ((col * 2) ^ ((row & 7) << 4))) = __float2bfloat16(Yacc[mt][nt][r]);
            }
    WAITLG0();
    WAITVM4();   // P0 landed, P1 in flight
    SBAR();

    // ---- projection: OUT[64][512] = Y @ Wproj + b; 16 stages, 3-slot ring ----
    // invariant at stage ps: ps published; ps+1 in flight; issue ps+2 (slot(ps-1), freed)
    f32x4 Pacc[2][8];
#pragma unroll
    for (int a = 0; a < 2; ++a)
#pragma unroll
        for (int b = 0; b < 8; ++b) Pacc[a][b] = (f32x4){0.f, 0.f, 0.f, 0.f};
    int pcur = 0;
#pragma unroll 1
    for (int ps = 0; ps < 16; ++ps) {
        int t = ps & 7;
        const char* pb = pring + pcur * 16384;
        int r0 = 32 * wr + lm;
        bf16x8 af0 = *(const bf16x8*)(ysb + r0 * 512
                        + ((t * 64 + quad * 16) ^ ((r0 & 7) << 4)));
        bf16x8 af1 = *(const bf16x8*)(ysb + (r0 + 16) * 512
                        + ((t * 64 + quad * 16) ^ ((r0 & 7) << 4)));
        bf16x8 bfr[8];
#pragma unroll
        for (int nt = 0; nt < 8; ++nt) {
            int rown = 128 * wc + 16 * nt + lm;
            bfr[nt] = *(const bf16x8*)(pb + rown * 64 + (swzB << 4));
        }
        if (ps + 2 <= 15) {   // issue P(ps+2) into slot (pcur+2)%3 == slot(ps-1)
            int ns = pcur + 2; if (ns >= 3) ns -= 3;
            const char* sp = stream + ((size_t)(130 + ps) << 14) + tid * 16;
            char* dp = pring + ns * 16384 + woff;
            GLDS16(sp, dp); GLDS16(sp + 4096, dp + 4096);
            GLDS16(sp + 8192, dp + 8192); GLDS16(sp + 12288, dp + 12288);
        }
        __builtin_amdgcn_s_setprio(1);
#pragma unroll
        for (int nt = 0; nt < 8; ++nt) {
            Pacc[0][nt] = MFMA16(af0, bfr[nt], Pacc[0][nt]);
            Pacc[1][nt] = MFMA16(af1, bfr[nt], Pacc[1][nt]);
        }
        __builtin_amdgcn_s_setprio(0);
        if (ps <= 13) WAITVM4();      // P(ps+1) landed; P(ps+2)'s 4 in flight
        else if (ps == 14) WAITVM0(); // P15 landed (+ epilogue stores drained)
        if (ps < 15) SBAR();          // publish P(ps+1); slot(ps) freed
        if (t == 7) {   // epilogue for p = ps>>3 (after barrier: stores off the wait path)
            int p = ps >> 3;
#pragma unroll
            for (int nt = 0; nt < 8; ++nt) {
                int col = 256 * p + 128 * wc + 16 * nt + lm;
                float bv = f32m ? ((const float*)bp)[col] : bf2f(((const __hip_bfloat16*)bp)[col]);
#pragma unroll
                for (int mt = 0; mt < 2; ++mt)
#pragma unroll
                    for (int r = 0; r < 4; ++r) {
                        int row = m0 + 32 * wr + 16 * mt + quad * 4 + r;
                        float v = Pacc[mt][nt][r] + bv;
                        if (f32m) ((float*)outp)[(size_t)row * 512 + col] = v;
                        else ((__hip_bfloat16*)outp)[(size_t)row * 512 + col] = __float2bfloat16(v);
                    }
            }
            if (ps < 15) {
#pragma unroll
                for (int a = 0; a < 2; ++a)
#pragma unroll
                    for (int b = 0; b < 8; ++b) Pacc[a][b] = (f32x4){0.f, 0.f, 0.f, 0.f};
            }
        }
        pcur = (pcur < 2) ? pcur + 1 : 0;
    }
}

extern "C" void kernel_launch(void* const* d_in, const int* in_sizes, int n_in,
                              void* d_out, int out_size, void* d_ws, size_t ws_size,
                              hipStream_t stream) {
    const void* x  = d_in[0];
    const void* wg = d_in[1];
    const void* w1 = d_in[2];
    const void* w2 = d_in[3];
    const void* wp = d_in[4];
    const void* bp = d_in[5];

    char* wstream = (char*)d_ws;   // 144 x 16384 = 2359296 B

    k_prep<<<144, 256, 0, stream>>>(w1, w2, wp, (const unsigned short*)x, wstream);
    k_moe<<<1024, 256, 81920, stream>>>(x, wg, wstream, bp, d_out);
}